// Round 12
// baseline (218.355 us; speedup 1.0000x reference)
//
#include <hip/hip_runtime.h>

typedef unsigned int u32;
typedef unsigned short u16;
typedef _Float16 f16;
typedef __attribute__((ext_vector_type(8))) _Float16 f16x8;
typedef __attribute__((ext_vector_type(4))) float f32x4;

#define MARGIN 1e-2f
#define LSC 2048.0f          // lo-split scale (keeps lo terms normal in f16)
#define LSCI (1.0f/2048.0f)

__device__ __forceinline__ u16 f16b(float f) {
    return __builtin_bit_cast(u16, (f16)f);
}
__device__ __forceinline__ f32x4 MF(f16x8 a, f16x8 b, f32x4 c) {
    return __builtin_amdgcn_mfma_f32_16x16x32_f16(a, b, c, 0, 0, 0);
}
__device__ __forceinline__ uint4 pack8(const u16 v[8]) {
    uint4 pk;
    pk.x = (u32)v[0] | ((u32)v[1] << 16);
    pk.y = (u32)v[2] | ((u32)v[3] << 16);
    pk.z = (u32)v[4] | ((u32)v[5] << 16);
    pk.w = (u32)v[6] | ((u32)v[7] << 16);
    return pk;
}

// ---------------------------------------------------------------------------
// conv: weights -> f16 MFMA-fragment-linear layouts (hi + scaled-lo for the
// exact-fix path). frag(nf,kk) of [K x N]: lane l (ln=l&15, quad=l>>4) holds
// 8 f16 = W[kk*32+quad*8+j][nf*16+ln], at (nf*8+kk)*512 + l*8 (u16 units).
// ---------------------------------------------------------------------------
__global__ __launch_bounds__(256) void conv_kernel(
    const float* __restrict__ Wt1, const float* __restrict__ Wp1,
    const float* __restrict__ Wt2, const float* __restrict__ Wp2,
    u16* __restrict__ wt1f, u16* __restrict__ wt1g, u16* __restrict__ wp1f,
    u16* __restrict__ wt2f, u16* __restrict__ wt2g, u16* __restrict__ wp2f,
    u32* __restrict__ gcnt)
{
    __shared__ float tile[64][68];
    const int t = threadIdx.x;
    const int b = blockIdx.x;

    if (b == 112) {
        if (t == 0) gcnt[0] = 0;
        for (int cc = t; cc < 1024; cc += 256) {
            int kk = cc >> 6, l = cc & 63, ln = l & 15, quad = l >> 4;
            u16 vh[8], vl[8];
            #pragma unroll
            for (int j = 0; j < 8; ++j) {
                int k = kk * 32 + quad * 8 + j;
                float f = (ln < 10) ? Wt2[k * 10 + ln] : 0.f;
                f16 h = (f16)f;
                vh[j] = __builtin_bit_cast(u16, h);
                vl[j] = f16b(LSC * (f - (float)h));
            }
            *(uint4*)(wt2f + kk * 512 + l * 8) = pack8(vh);
            *(uint4*)(wt2g + kk * 512 + l * 8) = pack8(vl);
        }
        for (int cc = t; cc < 2560; cc += 256) {
            int p = cc >> 8, rem = cc & 255, kk = rem >> 6, l = rem & 63;
            int ln = l & 15, quad = (l >> 4) & 3;
            u16 v[8];
            #pragma unroll
            for (int j = 0; j < 8; ++j) {
                int k = kk * 32 + quad * 8 + j;
                v[j] = f16b(ln < 10 ? Wp2[p * 1280 + k * 10 + ln] : 0.f);
            }
            *(uint4*)(wp2f + p * 2048 + kk * 512 + l * 8) = pack8(v);
        }
        return;
    }

    const float* src; int src_ld;
    u16 *dsth, *dstl; int nf0, kk0;
    if (b < 32) {
        int kt = b & 3, nt = b >> 2;
        src = Wt1 + (size_t)(kt * 64) * 512 + nt * 64; src_ld = 512;
        dsth = wt1f; dstl = wt1g; nf0 = nt * 4; kk0 = kt * 2;
    } else {
        int j = b - 32, p = j >> 3, r = j & 7;
        int kt = r & 3, nt = r >> 2;
        src = Wp1 + (size_t)p * 32768 + (size_t)(kt * 64) * 128 + nt * 64; src_ld = 128;
        dsth = wp1f + p * 32768; dstl = nullptr; nf0 = nt * 4; kk0 = kt * 2;
    }
    {
        const int kr = t >> 2, c0 = (t & 3) * 16;
        #pragma unroll
        for (int u = 0; u < 4; ++u) {
            float4 v = *(const float4*)(src + (size_t)kr * src_ld + c0 + u * 4);
            tile[kr][c0 + u*4 + 0] = v.x;
            tile[kr][c0 + u*4 + 1] = v.y;
            tile[kr][c0 + u*4 + 2] = v.z;
            tile[kr][c0 + u*4 + 3] = v.w;
        }
    }
    __syncthreads();
    #pragma unroll
    for (int s = 0; s < 2; ++s) {
        int cc = t + 256 * s;
        int l = cc & 63, fp = cc >> 6, nfl = fp >> 1, kkl = fp & 1;
        int ln = l & 15, quad = (l >> 4) & 3;
        int nloc = nfl * 16 + ln, kloc = kkl * 32 + quad * 8;
        u16 vh[8], vl[8];
        #pragma unroll
        for (int j = 0; j < 8; ++j) {
            float f = tile[kloc + j][nloc];
            f16 h = (f16)f;
            vh[j] = __builtin_bit_cast(u16, h);
            vl[j] = f16b(LSC * (f - (float)h));
        }
        size_t off = (size_t)((nf0 + nfl) * 8 + (kk0 + kkl)) * 512 + l * 8;
        *(uint4*)(dsth + off) = pack8(vh);
        if (dstl) *(uint4*)(dstl + off) = pack8(vl);
    }
}

// ---------------------------------------------------------------------------
// netsum (R5-exact, the measured 73 us / VGPR-52 / no-spill version):
// per 64-row block; layer-1 in 4 n-quarters, one B-frag per wave per kk
// with a 2-register rotating prefetch; hq stride 136; layer-2 on waves 0-3.
// ---------------------------------------------------------------------------
__global__ __launch_bounds__(512, 4) void netsum_kernel(
    const float* __restrict__ x, const float* __restrict__ bt1,
    const float* __restrict__ bt2,
    const float* __restrict__ bp1, const float* __restrict__ bp2,
    const int* __restrict__ rdd,
    const u16* __restrict__ wt1f, const u16* __restrict__ wp1f,
    const u16* __restrict__ wt2f, const u16* __restrict__ wp2f,
    float* __restrict__ out, u32* __restrict__ gcnt, u32* __restrict__ glist)
{
    __shared__ u16 xf[64][264];      // 33792 B
    __shared__ u16 scratch[17408];   // 34816 B  hq[64][136] (layer1) / hp 8x2176 (patch)
    __shared__ float lg[64][10];
    __shared__ float oacc[64][10];
    __shared__ u32 plist[10][64];
    __shared__ u32 pcnt[10];
    __shared__ int rdds[20];
    __shared__ u32 wq[40];
    __shared__ u32 nwork;
    // total ~76.6 KB -> 2 blocks/CU

    const int t = threadIdx.x;
    const int lane = t & 63;
    const int w = t >> 6;
    const int ln = lane & 15;
    const int quad = lane >> 4;
    const int row0 = blockIdx.x * 64;

    if (t < 10) pcnt[t] = 0;
    if (t < 20) rdds[t] = rdd[t];
    if (t == 0) nwork = 0;
    for (int i = t; i < 640; i += 512) ((float*)oacc)[i] = 0.f;

    // ---- stage x -> f16 LDS (coalesced) ----
    #pragma unroll
    for (int i = 0; i < 8; ++i) {
        int f = t + 512 * i;           // float4 index 0..4095
        int r = f >> 6, c4 = f & 63;
        float4 v = *(const float4*)(x + (size_t)(row0 + r) * 256 + c4 * 4);
        u16 q0 = f16b(v.x), q1 = f16b(v.y), q2 = f16b(v.z), q3 = f16b(v.w);
        uint2 pw = { (u32)q0 | ((u32)q1 << 16), (u32)q2 | ((u32)q3 << 16) };
        *(uint2*)&xf[r][c4 * 4] = pw;
    }
    __syncthreads();

    // ---- layer 1 in 4 n-quarters + layer-2 accumulation (waves 0..3) ----
    f32x4 acc2 = (f32x4){0.f, 0.f, 0.f, 0.f};
    u16* hq = scratch;                       // [64][136]
    for (int q = 0; q < 4; ++q) {
        f32x4 acc[4];
        #pragma unroll
        for (int m = 0; m < 4; ++m) acc[m] = (f32x4){0.f,0.f,0.f,0.f};
        // wave w owns n = q*128 + w*16 + ln  (frag nf = q*8 + w)
        const u16* bb = wt1f + (size_t)((q * 8 + w) * 8) * 512 + (size_t)lane * 8;
        f16x8 wc = *(const f16x8*)bb;              // kk = 0
        #pragma unroll
        for (int kk = 0; kk < 8; ++kk) {
            f16x8 wn = wc;
            if (kk < 7) wn = *(const f16x8*)(bb + (kk + 1) * 512);
            #pragma unroll
            for (int m = 0; m < 4; ++m) {
                f16x8 a = *(const f16x8*)(&xf[m * 16 + ln][kk * 32 + quad * 8]);
                acc[m] = MF(a, wc, acc[m]);
            }
            wc = wn;
        }
        // bias + relu + f16 -> hq [64][136]
        {
            const int nloc = w * 16 + ln;
            const float bias = bt1[q * 128 + nloc];
            #pragma unroll
            for (int m = 0; m < 4; ++m)
                #pragma unroll
                for (int r = 0; r < 4; ++r) {
                    float hv = acc[m][r] + bias; hv = hv > 0.f ? hv : 0.f;
                    hq[(m * 16 + quad * 4 + r) * 136 + nloc] = f16b(hv);
                }
        }
        __syncthreads();
        // layer 2 partial over this quarter's K=128 (waves 0..3, 16 rows each)
        if (w < 4) {
            #pragma unroll
            for (int kk2 = 0; kk2 < 4; ++kk2) {
                f16x8 ha = *(const f16x8*)(&hq[(w * 16 + ln) * 136 + kk2 * 32 + quad * 8]);
                f16x8 wb = *(const f16x8*)(wt2f + (q * 4 + kk2) * 512 + lane * 8);
                acc2 = MF(ha, wb, acc2);
            }
        }
        __syncthreads();   // before next quarter overwrites hq
    }
    if (w < 4 && ln < 10) {
        #pragma unroll
        for (int r = 0; r < 4; ++r)
            lg[w * 16 + quad * 4 + r][ln] = acc2[r] + bt2[ln];
    }
    __syncthreads();

    // ---- margin flag (-> global list) + bitmap + per-patch row lists ----
    if (t < 64) {
        float l[10];
        #pragma unroll
        for (int c = 0; c < 10; ++c) l[c] = lg[t][c];
        float b0v = -1e30f; int i0 = 0;
        #pragma unroll
        for (int c = 0; c < 10; ++c) if (l[c] > b0v) { b0v = l[c]; i0 = c; }
        float b1v = -1e30f; int i1 = 0;
        #pragma unroll
        for (int c = 0; c < 10; ++c) { if (c == i0) continue; if (l[c] > b1v) { b1v = l[c]; i1 = c; } }
        float b2v = -1e30f;
        #pragma unroll
        for (int c = 0; c < 10; ++c) { if (c == i0 || c == i1) continue; if (l[c] > b2v) b2v = l[c]; }
        if (b0v - b1v < MARGIN || b1v - b2v < MARGIN) {
            u32 idx = atomicAdd(gcnt, 1u);
            glist[idx] = (u32)(row0 + t);
        }
        u32 exact = 0, fb = 0;
        #pragma unroll
        for (int p = 0; p < 10; ++p) {
            int a = rdds[2 * p], bq = rdds[2 * p + 1];
            if (i0 == a && i1 == bq) exact |= 1u << p;
            if (i0 == a)             fb    |= 1u << p;
        }
        u32 bits = exact ? exact : fb;
        while (bits) {
            int p = __ffs(bits) - 1;
            bits &= bits - 1;
            u32 idx = atomicAdd(&pcnt[p], 1u);
            plist[p][idx] = (u32)t;
        }
    }
    __syncthreads();
    if (t < 10) {
        int L = (int)pcnt[t];
        for (int base = 0; base < L; base += 16) {
            u32 e = atomicAdd(&nwork, 1u);
            wq[e] = ((u32)t << 8) | (u32)base;
        }
    }
    __syncthreads();

    // ---- gated patch nets: n in 2 groups of 4 frags, rotating prefetch ----
    {
        const u32 nw = nwork;
        for (u32 ii = w; ii < nw; ii += 8) {
            const u32 item = wq[ii];
            const int p = (int)(item >> 8), mbase = (int)(item & 255);
            const int Lp = (int)pcnt[p];
            const int mi = mbase + ln;
            const int arow = (mi < Lp) ? (int)plist[p][mi] : (int)plist[p][0];
            const u16* xr = &xf[arow][0];
            const u16* wb = wp1f + (size_t)p * 32768 + (size_t)lane * 8;
            u16* hp = &scratch[w * 2176];            // [16][136]
            #pragma unroll
            for (int g = 0; g < 2; ++g) {
                f32x4 acc4[4];
                #pragma unroll
                for (int i2 = 0; i2 < 4; ++i2) acc4[i2] = (f32x4){0.f,0.f,0.f,0.f};
                f16x8 wc4[4];
                #pragma unroll
                for (int i2 = 0; i2 < 4; ++i2)
                    wc4[i2] = *(const f16x8*)(wb + ((g * 4 + i2) * 8 + 0) * 512);
                #pragma unroll
                for (int kk = 0; kk < 8; ++kk) {
                    f16x8 wn4[4];
                    #pragma unroll
                    for (int i2 = 0; i2 < 4; ++i2) {
                        wn4[i2] = wc4[i2];
                        if (kk < 7)
                            wn4[i2] = *(const f16x8*)(wb + ((g * 4 + i2) * 8 + kk + 1) * 512);
                    }
                    f16x8 a = *(const f16x8*)(xr + kk * 32 + quad * 8);
                    #pragma unroll
                    for (int i2 = 0; i2 < 4; ++i2) acc4[i2] = MF(a, wc4[i2], acc4[i2]);
                    #pragma unroll
                    for (int i2 = 0; i2 < 4; ++i2) wc4[i2] = wn4[i2];
                }
                #pragma unroll
                for (int i2 = 0; i2 < 4; ++i2) {
                    const int i2g = g * 4 + i2;
                    float bias = bp1[p * 128 + i2g * 16 + ln];
                    #pragma unroll
                    for (int r = 0; r < 4; ++r) {
                        float hv = acc4[i2][r] + bias; hv = hv > 0.f ? hv : 0.f;
                        hp[(quad * 4 + r) * 136 + i2g * 16 + ln] = f16b(hv);
                    }
                }
            }
            f32x4 po = (f32x4){0.f,0.f,0.f,0.f};
            #pragma unroll
            for (int kk = 0; kk < 4; ++kk) {
                f16x8 ha = *(const f16x8*)(&hp[ln * 136 + kk * 32 + quad * 8]);
                f16x8 wb2 = *(const f16x8*)(wp2f + p * 2048 + kk * 512 + lane * 8);
                po = MF(ha, wb2, po);
            }
            if (ln < 10) {
                float b2 = bp2[p * 10 + ln];
                #pragma unroll
                for (int r = 0; r < 4; ++r) {
                    int mi2 = mbase + quad * 4 + r;
                    if (mi2 < Lp)
                        atomicAdd(&oacc[plist[p][mi2]][ln], po[r] + b2);
                }
            }
        }
    }
    __syncthreads();

    for (int i = t; i < 640; i += 512)
        out[(size_t)row0 * 10 + i] = ((float*)lg)[i] + ((float*)oacc)[i];
}

// ---- fix v2 layer-1 macros (16-row blocks) ----
#define FLD(S,KK) \
    S##h0 = *(const f16x8*)(bbh + (KK)*512); \
    S##h1 = *(const f16x8*)(bbh + 4096 + (KK)*512); \
    S##l0 = *(const f16x8*)(bbl + (KK)*512); \
    S##l1 = *(const f16x8*)(bbl + 4096 + (KK)*512);
#define FCP(S,KK) { \
    f16x8 ah_=*(const f16x8*)(&xfh[ln][(KK)*32+quad*8]); \
    f16x8 al_=*(const f16x8*)(&xfl[ln][(KK)*32+quad*8]); \
    accH0=MF(ah_,S##h0,accH0); accS0=MF(ah_,S##l0,accS0); accS0=MF(al_,S##h0,accS0); \
    accH1=MF(ah_,S##h1,accH1); accS1=MF(ah_,S##l1,accS1); accS1=MF(al_,S##h1,accS1); }
#define F2L(WH, WL, KK) \
    WH = *(const f16x8*)(wt2f + (hl*8+(KK))*512 + lane*8); \
    WL = *(const f16x8*)(wt2g + (hl*8+(KK))*512 + lane*8);
#define F2C(WH, WL, KK) { int hidx_ = ln*264 + (KK)*32 + quad*8; \
    f16x8 hah_=*(const f16x8*)(&hb2[0][hidx_]); f16x8 hal_=*(const f16x8*)(&hb2[1][hidx_]); \
    acc2h=MF(hah_,WH,acc2h); acc2s=MF(hah_,WL,acc2s); acc2s=MF(hal_,WH,acc2s); }

// ---------------------------------------------------------------------------
// fix v2: 16-row blocks, grid 1024 (~206 active at ~3300 flagged rows vs 52
// before -> 4x CU coverage; LDS 69 KB -> 2 blocks/CU). Same split-f16
// numerics (hi + 2048*lo, ~1e-7 logits) -> exact bitmap; patch nets f16 MFMA.
// ---------------------------------------------------------------------------
__global__ __launch_bounds__(512, 2) void fix_kernel(
    const float* __restrict__ x, const float* __restrict__ bt1,
    const float* __restrict__ bt2,
    const float* __restrict__ bp1, const float* __restrict__ bp2,
    const int* __restrict__ rdd,
    const u16* __restrict__ wt1f, const u16* __restrict__ wt1g,
    const u16* __restrict__ wt2f, const u16* __restrict__ wt2g,
    const u16* __restrict__ wp1f, const u16* __restrict__ wp2f,
    const u32* __restrict__ gcnt, const u32* __restrict__ glist,
    float* __restrict__ out)
{
    __shared__ u16 xfh[16][264];     // 8448 B
    __shared__ u16 xfl[16][264];     // 8448 B
    __shared__ u16 hb2[2][4224];     // 16896 B  h hi/lo for one 256-col half
    __shared__ u16 hpbuf[17408];     // 34816 B  patch hp, 8 x [16][136]
    __shared__ float lgx[16][10];
    __shared__ float oacc[16][10];
    __shared__ u32 rows[16];
    __shared__ u32 plist[10][16];
    __shared__ u32 pcnt[10];
    __shared__ int rdds[20];
    __shared__ u32 wq[16];
    __shared__ u32 nwork;
    // ~69.5 KB -> 2 blocks/CU

    const int t = threadIdx.x;
    const int lane = t & 63;
    const int w = t >> 6;
    const int ln = lane & 15;
    const int quad = lane >> 4;
    const u32 cnt = gcnt[0];
    if (t < 20) rdds[t] = rdd[t];

    for (u32 base = blockIdx.x * 16; base < cnt; base += gridDim.x * 16) {
        __syncthreads();                       // protect buffers from prev iter
        const int R = (int)min(16u, cnt - base);
        if (t < 16) rows[t] = glist[base + (t < R ? t : 0)];
        if (t < 10) pcnt[t] = 0;
        if (t == 0) nwork = 0;
        if (t < 160) {
            ((float*)lgx)[t] = bt2[t % 10];
            ((float*)oacc)[t] = 0.f;
        }
        __syncthreads();

        // ---- gather flagged x rows -> hi/lo f16 LDS (16 rows = 1024 float4) ----
        #pragma unroll
        for (int i = 0; i < 2; ++i) {
            int f = t + 512 * i;
            int r = f >> 6, c4 = f & 63;
            float4 v = *(const float4*)(x + (size_t)rows[r] * 256 + c4 * 4);
            f16 h0 = (f16)v.x, h1 = (f16)v.y, h2 = (f16)v.z, h3 = (f16)v.w;
            u16 q0 = __builtin_bit_cast(u16, h0), q1 = __builtin_bit_cast(u16, h1);
            u16 q2 = __builtin_bit_cast(u16, h2), q3 = __builtin_bit_cast(u16, h3);
            u16 l0 = f16b(LSC * (v.x - (float)h0)), l1 = f16b(LSC * (v.y - (float)h1));
            u16 l2 = f16b(LSC * (v.z - (float)h2)), l3 = f16b(LSC * (v.w - (float)h3));
            uint2 hw = { (u32)q0 | ((u32)q1 << 16), (u32)q2 | ((u32)q3 << 16) };
            uint2 lw = { (u32)l0 | ((u32)l1 << 16), (u32)l2 | ((u32)l3 << 16) };
            *(uint2*)&xfh[r][c4 * 4] = hw;
            *(uint2*)&xfl[r][c4 * 4] = lw;
        }
        __syncthreads();

        // ---- layer 1 split-f16 (3 MFMA) + layer 2 split-f16, per 256-col half ----
        f32x4 acc2h = (f32x4){0.f,0.f,0.f,0.f};
        f32x4 acc2s = (f32x4){0.f,0.f,0.f,0.f};
        for (int hl = 0; hl < 2; ++hl) {
            f32x4 accH0 = (f32x4){0.f,0.f,0.f,0.f}, accH1 = accH0;
            f32x4 accS0 = accH0, accS1 = accH0;
            const size_t boff = (size_t)(hl * 16 + w * 2) * 4096 + (size_t)lane * 8;
            const u16* bbh = wt1f + boff;
            const u16* bbl = wt1g + boff;
            f16x8 ch0, ch1, cl0, cl1, nh0, nh1, nl0, nl1;
            FLD(c,0);
            FLD(n,1); FCP(c,0);
            FLD(c,2); FCP(n,1);
            FLD(n,3); FCP(c,2);
            FLD(c,4); FCP(n,3);
            FLD(n,5); FCP(c,4);
            FLD(c,6); FCP(n,5);
            FLD(n,7); FCP(c,6);
            FCP(n,7);
            // bias + relu + hi/lo split -> hb2 (rows = quad*4+r, cols w*32+i2*16+ln)
            #pragma unroll
            for (int i2 = 0; i2 < 2; ++i2) {
                int nloc = w * 32 + i2 * 16 + ln;
                float bias = bt1[hl * 256 + nloc];
                #pragma unroll
                for (int r = 0; r < 4; ++r) {
                    float hv = (i2 == 0 ? accH0[r] + accS0[r] * LSCI
                                        : accH1[r] + accS1[r] * LSCI) + bias;
                    hv = hv > 0.f ? hv : 0.f;
                    f16 hh = (f16)hv;
                    int idx = (quad * 4 + r) * 264 + nloc;
                    hb2[0][idx] = __builtin_bit_cast(u16, hh);
                    hb2[1][idx] = f16b(LSC * (hv - (float)hh));
                }
            }
            __syncthreads();
            // layer-2 partial: waves 0..3, wave w takes kk = {w, w+4}
            if (w < 4) {
                f16x8 whA, wlA, whB, wlB;
                F2L(whA, wlA, w);
                F2L(whB, wlB, w + 4);
                F2C(whA, wlA, w);
                F2C(whB, wlB, w + 4);
            }
            __syncthreads();   // before next half overwrites hb2
        }
        if (w < 4 && ln < 10) {
            #pragma unroll
            for (int r = 0; r < 4; ++r)
                atomicAdd(&lgx[quad * 4 + r][ln], acc2h[r] + acc2s[r] * LSCI);
        }
        __syncthreads();

        // ---- exact bitmap + per-patch row lists ----
        if (t < R) {
            float l[10];
            #pragma unroll
            for (int c = 0; c < 10; ++c) l[c] = lgx[t][c];
            float b0v = -1e30f; int i0 = 0;
            #pragma unroll
            for (int c = 0; c < 10; ++c) if (l[c] > b0v) { b0v = l[c]; i0 = c; }
            float b1v = -1e30f; int i1 = 0;
            #pragma unroll
            for (int c = 0; c < 10; ++c) { if (c == i0) continue; if (l[c] > b1v) { b1v = l[c]; i1 = c; } }
            u32 exact = 0, fb = 0;
            #pragma unroll
            for (int p = 0; p < 10; ++p) {
                int a = rdds[2 * p], bq = rdds[2 * p + 1];
                if (i0 == a && i1 == bq) exact |= 1u << p;
                if (i0 == a)             fb    |= 1u << p;
            }
            u32 bits = exact ? exact : fb;
            while (bits) {
                int p = __ffs(bits) - 1;
                bits &= bits - 1;
                u32 idx = atomicAdd(&pcnt[p], 1u);
                plist[p][idx] = (u32)t;
            }
        }
        __syncthreads();
        if (t < 10 && pcnt[t] > 0) {
            u32 e = atomicAdd(&nwork, 1u);
            wq[e] = (u32)t;
        }
        __syncthreads();

        // ---- patch nets: f16 MFMA, rotating 4-frag prefetch (16-row tiles) ----
        {
            const u32 nw = nwork;
            for (u32 ii = w; ii < nw; ii += 8) {
                const int p = (int)wq[ii];
                const int Lp = (int)pcnt[p];
                const int arow = (ln < Lp) ? (int)plist[p][ln] : (int)plist[p][0];
                const u16* xr = &xfh[arow][0];
                const u16* wb = wp1f + (size_t)p * 32768 + (size_t)lane * 8;
                u16* hp = &hpbuf[w * 2176];          // [16][136]
                #pragma unroll
                for (int g = 0; g < 2; ++g) {
                    f32x4 acc4[4];
                    #pragma unroll
                    for (int i2 = 0; i2 < 4; ++i2) acc4[i2] = (f32x4){0.f,0.f,0.f,0.f};
                    f16x8 wc4[4];
                    #pragma unroll
                    for (int i2 = 0; i2 < 4; ++i2)
                        wc4[i2] = *(const f16x8*)(wb + ((g * 4 + i2) * 8 + 0) * 512);
                    #pragma unroll
                    for (int kk = 0; kk < 8; ++kk) {
                        f16x8 wn4[4];
                        #pragma unroll
                        for (int i2 = 0; i2 < 4; ++i2) {
                            wn4[i2] = wc4[i2];
                            if (kk < 7)
                                wn4[i2] = *(const f16x8*)(wb + ((g * 4 + i2) * 8 + kk + 1) * 512);
                        }
                        f16x8 a = *(const f16x8*)(xr + kk * 32 + quad * 8);
                        #pragma unroll
                        for (int i2 = 0; i2 < 4; ++i2) acc4[i2] = MF(a, wc4[i2], acc4[i2]);
                        #pragma unroll
                        for (int i2 = 0; i2 < 4; ++i2) wc4[i2] = wn4[i2];
                    }
                    #pragma unroll
                    for (int i2 = 0; i2 < 4; ++i2) {
                        const int i2g = g * 4 + i2;
                        float bias = bp1[p * 128 + i2g * 16 + ln];
                        #pragma unroll
                        for (int r = 0; r < 4; ++r) {
                            float hv = acc4[i2][r] + bias; hv = hv > 0.f ? hv : 0.f;
                            hp[(quad * 4 + r) * 136 + i2g * 16 + ln] = f16b(hv);
                        }
                    }
                }
                f32x4 po = (f32x4){0.f,0.f,0.f,0.f};
                #pragma unroll
                for (int kk = 0; kk < 4; ++kk) {
                    f16x8 ha = *(const f16x8*)(&hp[ln * 136 + kk * 32 + quad * 8]);
                    f16x8 wb2 = *(const f16x8*)(wp2f + p * 2048 + kk * 512 + lane * 8);
                    po = MF(ha, wb2, po);
                }
                if (ln < 10) {
                    float b2 = bp2[p * 10 + ln];
                    #pragma unroll
                    for (int r = 0; r < 4; ++r) {
                        int mi2 = quad * 4 + r;
                        if (mi2 < Lp)
                            atomicAdd(&oacc[plist[p][mi2]][ln], po[r] + b2);
                    }
                }
            }
        }
        __syncthreads();

        if (t < R * 10) {
            int r = t / 10, c = t % 10;
            out[(size_t)rows[r] * 10 + c] = lgx[r][c] + oacc[r][c];
        }
    }
}

extern "C" void kernel_launch(void* const* d_in, const int* in_sizes, int n_in,
                              void* d_out, int out_size, void* d_ws, size_t ws_size,
                              hipStream_t stream) {
    const float* x   = (const float*)d_in[0];
    const float* Wt1 = (const float*)d_in[1];
    const float* bt1 = (const float*)d_in[2];
    const float* Wt2 = (const float*)d_in[3];
    const float* bt2 = (const float*)d_in[4];
    const float* Wp1 = (const float*)d_in[5];
    const float* bp1 = (const float*)d_in[6];
    const float* Wp2 = (const float*)d_in[7];
    const float* bp2 = (const float*)d_in[8];
    const int* rdd = (const int*)d_in[9];
    float* out = (float*)d_out;

    u16* wt1f = (u16*)d_ws;                 // 131072 u16
    u16* wt1g = wt1f + 131072;              // 131072 u16
    u16* wp1f = wt1g + 131072;              // 327680 u16
    u16* wt2f = wp1f + 327680;              // 8192 u16
    u16* wt2g = wt2f + 8192;                // 8192 u16
    u16* wp2f = wt2g + 8192;                // 20480 u16
    u32* gcnt  = (u32*)(wp2f + 20480);      // 1 (+pad to 16)
    u32* glist = gcnt + 16;                 // 65536 u32

    hipLaunchKernelGGL(conv_kernel, dim3(113), dim3(256), 0, stream,
                       Wt1, Wp1, Wt2, Wp2, wt1f, wt1g, wp1f, wt2f, wt2g, wp2f, gcnt);
    hipLaunchKernelGGL(netsum_kernel, dim3(1024), dim3(512), 0, stream,
                       x, bt1, bt2, bp1, bp2, rdd,
                       wt1f, wp1f, wt2f, wp2f, out, gcnt, glist);
    hipLaunchKernelGGL(fix_kernel, dim3(1024), dim3(512), 0, stream,
                       x, bt1, bt2, bp1, bp2, rdd,
                       wt1f, wt1g, wt2f, wt2g, wp1f, wp2f,
                       gcnt, glist, out);
}

// Round 13
// 193.330 us; speedup vs baseline: 1.1294x; 1.1294x over previous
//
#include <hip/hip_runtime.h>

typedef unsigned int u32;
typedef unsigned short u16;
typedef _Float16 f16;
typedef __attribute__((ext_vector_type(8))) _Float16 f16x8;
typedef __attribute__((ext_vector_type(4))) float f32x4;

#define MARGIN 1e-2f
#define LSC 2048.0f          // lo-split scale (keeps lo terms normal in f16)
#define LSCI (1.0f/2048.0f)

__device__ __forceinline__ u16 f16b(float f) {
    return __builtin_bit_cast(u16, (f16)f);
}
__device__ __forceinline__ f32x4 MF(f16x8 a, f16x8 b, f32x4 c) {
    return __builtin_amdgcn_mfma_f32_16x16x32_f16(a, b, c, 0, 0, 0);
}
__device__ __forceinline__ uint4 pack8(const u16 v[8]) {
    uint4 pk;
    pk.x = (u32)v[0] | ((u32)v[1] << 16);
    pk.y = (u32)v[2] | ((u32)v[3] << 16);
    pk.z = (u32)v[4] | ((u32)v[5] << 16);
    pk.w = (u32)v[6] | ((u32)v[7] << 16);
    return pk;
}

// ---------------------------------------------------------------------------
// conv: weights -> f16 MFMA-fragment-linear layouts (hi + scaled-lo for the
// exact-fix path). frag(nf,kk) of [K x N]: lane l (ln=l&15, quad=l>>4) holds
// 8 f16 = W[kk*32+quad*8+j][nf*16+ln], at (nf*8+kk)*512 + l*8 (u16 units).
// ---------------------------------------------------------------------------
__global__ __launch_bounds__(256) void conv_kernel(
    const float* __restrict__ Wt1, const float* __restrict__ Wp1,
    const float* __restrict__ Wt2, const float* __restrict__ Wp2,
    u16* __restrict__ wt1f, u16* __restrict__ wt1g, u16* __restrict__ wp1f,
    u16* __restrict__ wt2f, u16* __restrict__ wt2g, u16* __restrict__ wp2f,
    u32* __restrict__ gcnt)
{
    __shared__ float tile[64][68];
    const int t = threadIdx.x;
    const int b = blockIdx.x;

    if (b == 112) {
        if (t == 0) gcnt[0] = 0;
        for (int cc = t; cc < 1024; cc += 256) {
            int kk = cc >> 6, l = cc & 63, ln = l & 15, quad = l >> 4;
            u16 vh[8], vl[8];
            #pragma unroll
            for (int j = 0; j < 8; ++j) {
                int k = kk * 32 + quad * 8 + j;
                float f = (ln < 10) ? Wt2[k * 10 + ln] : 0.f;
                f16 h = (f16)f;
                vh[j] = __builtin_bit_cast(u16, h);
                vl[j] = f16b(LSC * (f - (float)h));
            }
            *(uint4*)(wt2f + kk * 512 + l * 8) = pack8(vh);
            *(uint4*)(wt2g + kk * 512 + l * 8) = pack8(vl);
        }
        for (int cc = t; cc < 2560; cc += 256) {
            int p = cc >> 8, rem = cc & 255, kk = rem >> 6, l = rem & 63;
            int ln = l & 15, quad = (l >> 4) & 3;
            u16 v[8];
            #pragma unroll
            for (int j = 0; j < 8; ++j) {
                int k = kk * 32 + quad * 8 + j;
                v[j] = f16b(ln < 10 ? Wp2[p * 1280 + k * 10 + ln] : 0.f);
            }
            *(uint4*)(wp2f + p * 2048 + kk * 512 + l * 8) = pack8(v);
        }
        return;
    }

    const float* src; int src_ld;
    u16 *dsth, *dstl; int nf0, kk0;
    if (b < 32) {
        int kt = b & 3, nt = b >> 2;
        src = Wt1 + (size_t)(kt * 64) * 512 + nt * 64; src_ld = 512;
        dsth = wt1f; dstl = wt1g; nf0 = nt * 4; kk0 = kt * 2;
    } else {
        int j = b - 32, p = j >> 3, r = j & 7;
        int kt = r & 3, nt = r >> 2;
        src = Wp1 + (size_t)p * 32768 + (size_t)(kt * 64) * 128 + nt * 64; src_ld = 128;
        dsth = wp1f + p * 32768; dstl = nullptr; nf0 = nt * 4; kk0 = kt * 2;
    }
    {
        const int kr = t >> 2, c0 = (t & 3) * 16;
        #pragma unroll
        for (int u = 0; u < 4; ++u) {
            float4 v = *(const float4*)(src + (size_t)kr * src_ld + c0 + u * 4);
            tile[kr][c0 + u*4 + 0] = v.x;
            tile[kr][c0 + u*4 + 1] = v.y;
            tile[kr][c0 + u*4 + 2] = v.z;
            tile[kr][c0 + u*4 + 3] = v.w;
        }
    }
    __syncthreads();
    #pragma unroll
    for (int s = 0; s < 2; ++s) {
        int cc = t + 256 * s;
        int l = cc & 63, fp = cc >> 6, nfl = fp >> 1, kkl = fp & 1;
        int ln = l & 15, quad = (l >> 4) & 3;
        int nloc = nfl * 16 + ln, kloc = kkl * 32 + quad * 8;
        u16 vh[8], vl[8];
        #pragma unroll
        for (int j = 0; j < 8; ++j) {
            float f = tile[kloc + j][nloc];
            f16 h = (f16)f;
            vh[j] = __builtin_bit_cast(u16, h);
            vl[j] = f16b(LSC * (f - (float)h));
        }
        size_t off = (size_t)((nf0 + nfl) * 8 + (kk0 + kkl)) * 512 + l * 8;
        *(uint4*)(dsth + off) = pack8(vh);
        if (dstl) *(uint4*)(dstl + off) = pack8(vl);
    }
}

// ---------------------------------------------------------------------------
// netsum (R5-exact, the measured 73 us / VGPR-52 / no-spill version), plus:
// flagged glist entries carry netsum's own top-2 pair (row | i0<<16 | i1<<20)
// so fix can early-out rows whose exact pair matches.
// ---------------------------------------------------------------------------
__global__ __launch_bounds__(512, 4) void netsum_kernel(
    const float* __restrict__ x, const float* __restrict__ bt1,
    const float* __restrict__ bt2,
    const float* __restrict__ bp1, const float* __restrict__ bp2,
    const int* __restrict__ rdd,
    const u16* __restrict__ wt1f, const u16* __restrict__ wp1f,
    const u16* __restrict__ wt2f, const u16* __restrict__ wp2f,
    float* __restrict__ out, u32* __restrict__ gcnt, u32* __restrict__ glist)
{
    __shared__ u16 xf[64][264];      // 33792 B
    __shared__ u16 scratch[17408];   // 34816 B  hq[64][136] (layer1) / hp 8x2176 (patch)
    __shared__ float lg[64][10];
    __shared__ float oacc[64][10];
    __shared__ u32 plist[10][64];
    __shared__ u32 pcnt[10];
    __shared__ int rdds[20];
    __shared__ u32 wq[40];
    __shared__ u32 nwork;
    // total ~76.6 KB -> 2 blocks/CU

    const int t = threadIdx.x;
    const int lane = t & 63;
    const int w = t >> 6;
    const int ln = lane & 15;
    const int quad = lane >> 4;
    const int row0 = blockIdx.x * 64;

    if (t < 10) pcnt[t] = 0;
    if (t < 20) rdds[t] = rdd[t];
    if (t == 0) nwork = 0;
    for (int i = t; i < 640; i += 512) ((float*)oacc)[i] = 0.f;

    // ---- stage x -> f16 LDS (coalesced) ----
    #pragma unroll
    for (int i = 0; i < 8; ++i) {
        int f = t + 512 * i;           // float4 index 0..4095
        int r = f >> 6, c4 = f & 63;
        float4 v = *(const float4*)(x + (size_t)(row0 + r) * 256 + c4 * 4);
        u16 q0 = f16b(v.x), q1 = f16b(v.y), q2 = f16b(v.z), q3 = f16b(v.w);
        uint2 pw = { (u32)q0 | ((u32)q1 << 16), (u32)q2 | ((u32)q3 << 16) };
        *(uint2*)&xf[r][c4 * 4] = pw;
    }
    __syncthreads();

    // ---- layer 1 in 4 n-quarters + layer-2 accumulation (waves 0..3) ----
    f32x4 acc2 = (f32x4){0.f, 0.f, 0.f, 0.f};
    u16* hq = scratch;                       // [64][136]
    for (int q = 0; q < 4; ++q) {
        f32x4 acc[4];
        #pragma unroll
        for (int m = 0; m < 4; ++m) acc[m] = (f32x4){0.f,0.f,0.f,0.f};
        // wave w owns n = q*128 + w*16 + ln  (frag nf = q*8 + w)
        const u16* bb = wt1f + (size_t)((q * 8 + w) * 8) * 512 + (size_t)lane * 8;
        f16x8 wc = *(const f16x8*)bb;              // kk = 0
        #pragma unroll
        for (int kk = 0; kk < 8; ++kk) {
            f16x8 wn = wc;
            if (kk < 7) wn = *(const f16x8*)(bb + (kk + 1) * 512);
            #pragma unroll
            for (int m = 0; m < 4; ++m) {
                f16x8 a = *(const f16x8*)(&xf[m * 16 + ln][kk * 32 + quad * 8]);
                acc[m] = MF(a, wc, acc[m]);
            }
            wc = wn;
        }
        // bias + relu + f16 -> hq [64][136]
        {
            const int nloc = w * 16 + ln;
            const float bias = bt1[q * 128 + nloc];
            #pragma unroll
            for (int m = 0; m < 4; ++m)
                #pragma unroll
                for (int r = 0; r < 4; ++r) {
                    float hv = acc[m][r] + bias; hv = hv > 0.f ? hv : 0.f;
                    hq[(m * 16 + quad * 4 + r) * 136 + nloc] = f16b(hv);
                }
        }
        __syncthreads();
        // layer 2 partial over this quarter's K=128 (waves 0..3, 16 rows each)
        if (w < 4) {
            #pragma unroll
            for (int kk2 = 0; kk2 < 4; ++kk2) {
                f16x8 ha = *(const f16x8*)(&hq[(w * 16 + ln) * 136 + kk2 * 32 + quad * 8]);
                f16x8 wb = *(const f16x8*)(wt2f + (q * 4 + kk2) * 512 + lane * 8);
                acc2 = MF(ha, wb, acc2);
            }
        }
        __syncthreads();   // before next quarter overwrites hq
    }
    if (w < 4 && ln < 10) {
        #pragma unroll
        for (int r = 0; r < 4; ++r)
            lg[w * 16 + quad * 4 + r][ln] = acc2[r] + bt2[ln];
    }
    __syncthreads();

    // ---- margin flag (-> global list with netsum's top-2 pair) + bitmap ----
    if (t < 64) {
        float l[10];
        #pragma unroll
        for (int c = 0; c < 10; ++c) l[c] = lg[t][c];
        float b0v = -1e30f; int i0 = 0;
        #pragma unroll
        for (int c = 0; c < 10; ++c) if (l[c] > b0v) { b0v = l[c]; i0 = c; }
        float b1v = -1e30f; int i1 = 0;
        #pragma unroll
        for (int c = 0; c < 10; ++c) { if (c == i0) continue; if (l[c] > b1v) { b1v = l[c]; i1 = c; } }
        float b2v = -1e30f;
        #pragma unroll
        for (int c = 0; c < 10; ++c) { if (c == i0 || c == i1) continue; if (l[c] > b2v) b2v = l[c]; }
        if (b0v - b1v < MARGIN || b1v - b2v < MARGIN) {
            u32 idx = atomicAdd(gcnt, 1u);
            glist[idx] = (u32)(row0 + t) | ((u32)i0 << 16) | ((u32)i1 << 20);
        }
        u32 exact = 0, fb = 0;
        #pragma unroll
        for (int p = 0; p < 10; ++p) {
            int a = rdds[2 * p], bq = rdds[2 * p + 1];
            if (i0 == a && i1 == bq) exact |= 1u << p;
            if (i0 == a)             fb    |= 1u << p;
        }
        u32 bits = exact ? exact : fb;
        while (bits) {
            int p = __ffs(bits) - 1;
            bits &= bits - 1;
            u32 idx = atomicAdd(&pcnt[p], 1u);
            plist[p][idx] = (u32)t;
        }
    }
    __syncthreads();
    if (t < 10) {
        int L = (int)pcnt[t];
        for (int base = 0; base < L; base += 16) {
            u32 e = atomicAdd(&nwork, 1u);
            wq[e] = ((u32)t << 8) | (u32)base;
        }
    }
    __syncthreads();

    // ---- gated patch nets: n in 2 groups of 4 frags, rotating prefetch ----
    {
        const u32 nw = nwork;
        for (u32 ii = w; ii < nw; ii += 8) {
            const u32 item = wq[ii];
            const int p = (int)(item >> 8), mbase = (int)(item & 255);
            const int Lp = (int)pcnt[p];
            const int mi = mbase + ln;
            const int arow = (mi < Lp) ? (int)plist[p][mi] : (int)plist[p][0];
            const u16* xr = &xf[arow][0];
            const u16* wb = wp1f + (size_t)p * 32768 + (size_t)lane * 8;
            u16* hp = &scratch[w * 2176];            // [16][136]
            #pragma unroll
            for (int g = 0; g < 2; ++g) {
                f32x4 acc4[4];
                #pragma unroll
                for (int i2 = 0; i2 < 4; ++i2) acc4[i2] = (f32x4){0.f,0.f,0.f,0.f};
                f16x8 wc4[4];
                #pragma unroll
                for (int i2 = 0; i2 < 4; ++i2)
                    wc4[i2] = *(const f16x8*)(wb + ((g * 4 + i2) * 8 + 0) * 512);
                #pragma unroll
                for (int kk = 0; kk < 8; ++kk) {
                    f16x8 wn4[4];
                    #pragma unroll
                    for (int i2 = 0; i2 < 4; ++i2) {
                        wn4[i2] = wc4[i2];
                        if (kk < 7)
                            wn4[i2] = *(const f16x8*)(wb + ((g * 4 + i2) * 8 + kk + 1) * 512);
                    }
                    f16x8 a = *(const f16x8*)(xr + kk * 32 + quad * 8);
                    #pragma unroll
                    for (int i2 = 0; i2 < 4; ++i2) acc4[i2] = MF(a, wc4[i2], acc4[i2]);
                    #pragma unroll
                    for (int i2 = 0; i2 < 4; ++i2) wc4[i2] = wn4[i2];
                }
                #pragma unroll
                for (int i2 = 0; i2 < 4; ++i2) {
                    const int i2g = g * 4 + i2;
                    float bias = bp1[p * 128 + i2g * 16 + ln];
                    #pragma unroll
                    for (int r = 0; r < 4; ++r) {
                        float hv = acc4[i2][r] + bias; hv = hv > 0.f ? hv : 0.f;
                        hp[(quad * 4 + r) * 136 + i2g * 16 + ln] = f16b(hv);
                    }
                }
            }
            f32x4 po = (f32x4){0.f,0.f,0.f,0.f};
            #pragma unroll
            for (int kk = 0; kk < 4; ++kk) {
                f16x8 ha = *(const f16x8*)(&hp[ln * 136 + kk * 32 + quad * 8]);
                f16x8 wb2 = *(const f16x8*)(wp2f + p * 2048 + kk * 512 + lane * 8);
                po = MF(ha, wb2, po);
            }
            if (ln < 10) {
                float b2 = bp2[p * 10 + ln];
                #pragma unroll
                for (int r = 0; r < 4; ++r) {
                    int mi2 = mbase + quad * 4 + r;
                    if (mi2 < Lp)
                        atomicAdd(&oacc[plist[p][mi2]][ln], po[r] + b2);
                }
            }
        }
    }
    __syncthreads();

    for (int i = t; i < 640; i += 512)
        out[(size_t)row0 * 10 + i] = ((float*)lg)[i] + ((float*)oacc)[i];
}

// ---- fix layer-1 macros ----
#define FLD(S,KK) \
    S##h0 = *(const f16x8*)(bbh + (KK)*512); \
    S##h1 = *(const f16x8*)(bbh + 4096 + (KK)*512); \
    S##l0 = *(const f16x8*)(bbl + (KK)*512); \
    S##l1 = *(const f16x8*)(bbl + 4096 + (KK)*512);
#define FCP(S,KK) { _Pragma("unroll") for (int m_=0;m_<4;++m_){ \
    f16x8 ah_=*(const f16x8*)(&xfh[m_*16+ln][(KK)*32+quad*8]); \
    f16x8 al_=*(const f16x8*)(&xfl[m_*16+ln][(KK)*32+quad*8]); \
    accH[m_][0]=MF(ah_,S##h0,accH[m_][0]); accS[m_][0]=MF(ah_,S##l0,accS[m_][0]); accS[m_][0]=MF(al_,S##h0,accS[m_][0]); \
    accH[m_][1]=MF(ah_,S##h1,accH[m_][1]); accS[m_][1]=MF(ah_,S##l1,accS[m_][1]); accS[m_][1]=MF(al_,S##h1,accS[m_][1]); } }
#define F2L(WH, WL, KK) \
    WH = *(const f16x8*)(wt2f + (hl*8+(KK))*512 + lane*8); \
    WL = *(const f16x8*)(wt2g + (hl*8+(KK))*512 + lane*8);
#define F2C(WH, WL, KK) { int hidx_=(w*16+ln)*264 + (KK)*32 + quad*8; \
    f16x8 hah_=*(const f16x8*)(&hb2[0][hidx_]); f16x8 hal_=*(const f16x8*)(&hb2[1][hidx_]); \
    acc2h=MF(hah_,WH,acc2h); acc2s=MF(hah_,WL,acc2s); acc2s=MF(hal_,WH,acc2s); }

// ---------------------------------------------------------------------------
// fix v3: v1's non-spilling structure + early-out. Exact split-f16 logits;
// rows whose exact top-2 pair equals netsum's stored pair are skipped
// entirely (netsum's output already valid). Only changed rows (rare) get
// patch recompute + out overwrite.
// ---------------------------------------------------------------------------
__global__ __launch_bounds__(512, 1) void fix_kernel(
    const float* __restrict__ x, const float* __restrict__ bt1,
    const float* __restrict__ bt2,
    const float* __restrict__ bp1, const float* __restrict__ bp2,
    const int* __restrict__ rdd,
    const u16* __restrict__ wt1f, const u16* __restrict__ wt1g,
    const u16* __restrict__ wt2f, const u16* __restrict__ wt2g,
    const u16* __restrict__ wp1f, const u16* __restrict__ wp2f,
    const u32* __restrict__ gcnt, const u32* __restrict__ glist,
    float* __restrict__ out)
{
    __shared__ u16 xfh[64][264];
    __shared__ u16 xfl[64][264];
    __shared__ u16 hb2[2][16896];
    __shared__ float lg[64][10];
    __shared__ float oacc[64][10];
    __shared__ u32 rows[64];
    __shared__ u32 nspair[64];
    __shared__ u32 chg[64];
    __shared__ u32 plist[10][64];
    __shared__ u32 pcnt[10];
    __shared__ int rdds[20];
    __shared__ u32 wq[40];
    __shared__ u32 nwork;

    const int t = threadIdx.x;
    const int lane = t & 63;
    const int w = t >> 6;
    const int ln = lane & 15;
    const int quad = lane >> 4;
    const u32 cnt = gcnt[0];
    if (t < 20) rdds[t] = rdd[t];

    for (u32 base = blockIdx.x * 64; base < cnt; base += gridDim.x * 64) {
        __syncthreads();
        const int R = (int)min(64u, cnt - base);
        if (t < 64) {
            u32 g = glist[base + (t < R ? t : 0)];
            rows[t] = g & 0xFFFFu;
            nspair[t] = (g >> 16) & 0xFFu;
            chg[t] = 0;
        }
        if (t < 10) pcnt[t] = 0;
        if (t == 0) nwork = 0;
        for (int i = t; i < 640; i += 512) ((float*)oacc)[i] = 0.f;
        __syncthreads();

        #pragma unroll
        for (int i = 0; i < 8; ++i) {
            int f = t + 512 * i;
            int r = f >> 6, c4 = f & 63;
            float4 v = *(const float4*)(x + (size_t)rows[r] * 256 + c4 * 4);
            f16 h0 = (f16)v.x, h1 = (f16)v.y, h2 = (f16)v.z, h3 = (f16)v.w;
            u16 q0 = __builtin_bit_cast(u16, h0), q1 = __builtin_bit_cast(u16, h1);
            u16 q2 = __builtin_bit_cast(u16, h2), q3 = __builtin_bit_cast(u16, h3);
            u16 l0 = f16b(LSC * (v.x - (float)h0)), l1 = f16b(LSC * (v.y - (float)h1));
            u16 l2 = f16b(LSC * (v.z - (float)h2)), l3 = f16b(LSC * (v.w - (float)h3));
            uint2 hw = { (u32)q0 | ((u32)q1 << 16), (u32)q2 | ((u32)q3 << 16) };
            uint2 lw = { (u32)l0 | ((u32)l1 << 16), (u32)l2 | ((u32)l3 << 16) };
            *(uint2*)&xfh[r][c4 * 4] = hw;
            *(uint2*)&xfl[r][c4 * 4] = lw;
        }
        __syncthreads();

        f32x4 acc2h = (f32x4){0.f,0.f,0.f,0.f};
        f32x4 acc2s = (f32x4){0.f,0.f,0.f,0.f};
        for (int hl = 0; hl < 2; ++hl) {
            f32x4 accH[4][2], accS[4][2];
            #pragma unroll
            for (int m = 0; m < 4; ++m)
                #pragma unroll
                for (int i2 = 0; i2 < 2; ++i2) {
                    accH[m][i2] = (f32x4){0.f,0.f,0.f,0.f};
                    accS[m][i2] = (f32x4){0.f,0.f,0.f,0.f};
                }
            const size_t boff = (size_t)(hl * 16 + w * 2) * 4096 + (size_t)lane * 8;
            const u16* bbh = wt1f + boff;
            const u16* bbl = wt1g + boff;
            f16x8 ch0, ch1, cl0, cl1, nh0, nh1, nl0, nl1;
            FLD(c,0);
            FLD(n,1); FCP(c,0);
            FLD(c,2); FCP(n,1);
            FLD(n,3); FCP(c,2);
            FLD(c,4); FCP(n,3);
            FLD(n,5); FCP(c,4);
            FLD(c,6); FCP(n,5);
            FLD(n,7); FCP(c,6);
            FCP(n,7);
            #pragma unroll
            for (int m = 0; m < 4; ++m)
                #pragma unroll
                for (int i2 = 0; i2 < 2; ++i2) {
                    int nloc = w * 32 + i2 * 16 + ln;
                    float bias = bt1[hl * 256 + nloc];
                    #pragma unroll
                    for (int r = 0; r < 4; ++r) {
                        float hv = accH[m][i2][r] + accS[m][i2][r] * LSCI + bias;
                        hv = hv > 0.f ? hv : 0.f;
                        f16 hh = (f16)hv;
                        int idx = (m * 16 + quad * 4 + r) * 264 + nloc;
                        hb2[0][idx] = __builtin_bit_cast(u16, hh);
                        hb2[1][idx] = f16b(LSC * (hv - (float)hh));
                    }
                }
            __syncthreads();
            if (w < 4) {
                f16x8 whc, wlc, whn, wln;
                F2L(whc, wlc, 0);
                F2L(whn, wln, 1); F2C(whc, wlc, 0);
                F2L(whc, wlc, 2); F2C(whn, wln, 1);
                F2L(whn, wln, 3); F2C(whc, wlc, 2);
                F2L(whc, wlc, 4); F2C(whn, wln, 3);
                F2L(whn, wln, 5); F2C(whc, wlc, 4);
                F2L(whc, wlc, 6); F2C(whn, wln, 5);
                F2L(whn, wln, 7); F2C(whc, wlc, 6);
                F2C(whn, wln, 7);
            }
            __syncthreads();
        }
        if (w < 4 && ln < 10) {
            #pragma unroll
            for (int r = 0; r < 4; ++r)
                lg[w * 16 + quad * 4 + r][ln] = acc2h[r] + acc2s[r] * LSCI + bt2[ln];
        }
        __syncthreads();

        // ---- exact top-2; early-out rows whose pair matches netsum's ----
        if (t < R) {
            float l[10];
            #pragma unroll
            for (int c = 0; c < 10; ++c) l[c] = lg[t][c];
            float b0v = -1e30f; int i0 = 0;
            #pragma unroll
            for (int c = 0; c < 10; ++c) if (l[c] > b0v) { b0v = l[c]; i0 = c; }
            float b1v = -1e30f; int i1 = 0;
            #pragma unroll
            for (int c = 0; c < 10; ++c) { if (c == i0) continue; if (l[c] > b1v) { b1v = l[c]; i1 = c; } }
            u32 ep = (u32)i0 | ((u32)i1 << 4);
            if (ep != nspair[t]) {
                chg[t] = 1;
                u32 exact = 0, fb = 0;
                #pragma unroll
                for (int p = 0; p < 10; ++p) {
                    int a = rdds[2 * p], bq = rdds[2 * p + 1];
                    if (i0 == a && i1 == bq) exact |= 1u << p;
                    if (i0 == a)             fb    |= 1u << p;
                }
                u32 bits = exact ? exact : fb;
                while (bits) {
                    int p = __ffs(bits) - 1;
                    bits &= bits - 1;
                    u32 idx = atomicAdd(&pcnt[p], 1u);
                    plist[p][idx] = (u32)t;
                }
            }
        }
        __syncthreads();
        if (t < 10) {
            int L = (int)pcnt[t];
            for (int b2i = 0; b2i < L; b2i += 16) {
                u32 e = atomicAdd(&nwork, 1u);
                wq[e] = ((u32)t << 8) | (u32)b2i;
            }
        }
        __syncthreads();

        // ---- patch nets (changed rows only; usually empty) ----
        {
            const u32 nw = nwork;
            u16* hbase = &hb2[0][0];
            for (u32 ii = w; ii < nw; ii += 8) {
                const u32 item = wq[ii];
                const int p = (int)(item >> 8), mbase = (int)(item & 255);
                const int Lp = (int)pcnt[p];
                const int mi = mbase + ln;
                const int arow = (mi < Lp) ? (int)plist[p][mi] : (int)plist[p][0];
                const u16* xr = &xfh[arow][0];
                const u16* wb = wp1f + (size_t)p * 32768 + (size_t)lane * 8;
                u16* hp = hbase + w * 2176;
                #pragma unroll
                for (int g = 0; g < 2; ++g) {
                    f32x4 acc4[4];
                    #pragma unroll
                    for (int i2 = 0; i2 < 4; ++i2) acc4[i2] = (f32x4){0.f,0.f,0.f,0.f};
                    f16x8 wc4[4];
                    #pragma unroll
                    for (int i2 = 0; i2 < 4; ++i2)
                        wc4[i2] = *(const f16x8*)(wb + ((g * 4 + i2) * 8 + 0) * 512);
                    #pragma unroll
                    for (int kk = 0; kk < 8; ++kk) {
                        f16x8 wn4[4];
                        #pragma unroll
                        for (int i2 = 0; i2 < 4; ++i2) {
                            wn4[i2] = wc4[i2];
                            if (kk < 7)
                                wn4[i2] = *(const f16x8*)(wb + ((g * 4 + i2) * 8 + kk + 1) * 512);
                        }
                        f16x8 a = *(const f16x8*)(xr + kk * 32 + quad * 8);
                        #pragma unroll
                        for (int i2 = 0; i2 < 4; ++i2) acc4[i2] = MF(a, wc4[i2], acc4[i2]);
                        #pragma unroll
                        for (int i2 = 0; i2 < 4; ++i2) wc4[i2] = wn4[i2];
                    }
                    #pragma unroll
                    for (int i2 = 0; i2 < 4; ++i2) {
                        const int i2g = g * 4 + i2;
                        float bias = bp1[p * 128 + i2g * 16 + ln];
                        #pragma unroll
                        for (int r = 0; r < 4; ++r) {
                            float hv = acc4[i2][r] + bias; hv = hv > 0.f ? hv : 0.f;
                            hp[(quad * 4 + r) * 136 + i2g * 16 + ln] = f16b(hv);
                        }
                    }
                }
                f32x4 po = (f32x4){0.f,0.f,0.f,0.f};
                #pragma unroll
                for (int kk = 0; kk < 4; ++kk) {
                    f16x8 ha = *(const f16x8*)(&hp[ln * 136 + kk * 32 + quad * 8]);
                    f16x8 wb2 = *(const f16x8*)(wp2f + p * 2048 + kk * 512 + lane * 8);
                    po = MF(ha, wb2, po);
                }
                if (ln < 10) {
                    float b2 = bp2[p * 10 + ln];
                    #pragma unroll
                    for (int r = 0; r < 4; ++r) {
                        int mi2 = mbase + quad * 4 + r;
                        if (mi2 < Lp)
                            atomicAdd(&oacc[plist[p][mi2]][ln], po[r] + b2);
                    }
                }
            }
        }
        __syncthreads();

        for (int i = t; i < R * 10; i += 512) {
            int r = i / 10, c = i % 10;
            if (chg[r])
                out[(size_t)rows[r] * 10 + c] = lg[r][c] + oacc[r][c];
        }
    }
}

extern "C" void kernel_launch(void* const* d_in, const int* in_sizes, int n_in,
                              void* d_out, int out_size, void* d_ws, size_t ws_size,
                              hipStream_t stream) {
    const float* x   = (const float*)d_in[0];
    const float* Wt1 = (const float*)d_in[1];
    const float* bt1 = (const float*)d_in[2];
    const float* Wt2 = (const float*)d_in[3];
    const float* bt2 = (const float*)d_in[4];
    const float* Wp1 = (const float*)d_in[5];
    const float* bp1 = (const float*)d_in[6];
    const float* Wp2 = (const float*)d_in[7];
    const float* bp2 = (const float*)d_in[8];
    const int* rdd = (const int*)d_in[9];
    float* out = (float*)d_out;

    u16* wt1f = (u16*)d_ws;                 // 131072 u16
    u16* wt1g = wt1f + 131072;              // 131072 u16
    u16* wp1f = wt1g + 131072;              // 327680 u16
    u16* wt2f = wp1f + 327680;              // 8192 u16
    u16* wt2g = wt2f + 8192;                // 8192 u16
    u16* wp2f = wt2g + 8192;                // 20480 u16
    u32* gcnt  = (u32*)(wp2f + 20480);      // 1 (+pad to 16)
    u32* glist = gcnt + 16;                 // 65536 u32

    hipLaunchKernelGGL(conv_kernel, dim3(113), dim3(256), 0, stream,
                       Wt1, Wp1, Wt2, Wp2, wt1f, wt1g, wp1f, wt2f, wt2g, wp2f, gcnt);
    hipLaunchKernelGGL(netsum_kernel, dim3(1024), dim3(512), 0, stream,
                       x, bt1, bt2, bp1, bp2, rdd,
                       wt1f, wp1f, wt2f, wp2f, out, gcnt, glist);
    hipLaunchKernelGGL(fix_kernel, dim3(256), dim3(512), 0, stream,
                       x, bt1, bt2, bp1, bp2, rdd,
                       wt1f, wt1g, wt2f, wt2g, wp1f, wp2f,
                       gcnt, glist, out);
}